// Round 4
// baseline (326.644 us; speedup 1.0000x reference)
//
#include <hip/hip_runtime.h>

typedef __bf16 bf16;
typedef bf16 bf16x8 __attribute__((ext_vector_type(8)));
typedef bf16 bf16x4 __attribute__((ext_vector_type(4)));
typedef float f32x4 __attribute__((ext_vector_type(4)));

#define B_ 4
#define N1 4096
#define N2 256
#define DIM 1024
#define HEADS 16
#define DH 64
#define INNER 1024
#define ASPLIT 4
#define KEYS_PER_SPLIT (N1 / ASPLIT)     // 1024
#define SPLIT_ELEMS (4 * 16 * 256 * 64)  // fp32 elems per split partial

// async global->LDS, 16B per lane; LDS dest = wave-uniform base + lane*16
typedef __attribute__((address_space(1))) const void gvoid_t;
typedef __attribute__((address_space(3))) void lvoid_t;
__device__ __forceinline__ void async16(const void* g, void* l) {
  __builtin_amdgcn_global_load_lds((gvoid_t*)g, (lvoid_t*)l, 16, 0, 0);
}

// raw barrier + partial vmcnt waits (prefetch stays in flight across barrier)
#define WAIT_VMCNT_4() asm volatile("s_waitcnt vmcnt(4)" ::: "memory")
#define WAIT_VMCNT_0() asm volatile("s_waitcnt vmcnt(0)" ::: "memory")
#define HW_BARRIER() asm volatile("s_barrier" ::: "memory")

// ---------------------------------------------------------------------------
// LayerNorm: fp32 (rows x 1024) -> bf16. One WAVE per row (no LDS, no barrier).
// ---------------------------------------------------------------------------
__global__ __launch_bounds__(256) void ln_kernel(const float* __restrict__ src,
                                                 const float* __restrict__ w,
                                                 const float* __restrict__ bb,
                                                 bf16* __restrict__ dst) {
  int wv = threadIdx.x >> 6, lane = threadIdx.x & 63;
  int row = blockIdx.x * 4 + wv;
  const float4* p = (const float4*)(src + (size_t)row * DIM);
  float4 v[4];
  for (int j = 0; j < 4; j++) v[j] = p[j * 64 + lane];
  float s = 0.f, sq = 0.f;
  for (int j = 0; j < 4; j++) {
    s += v[j].x + v[j].y + v[j].z + v[j].w;
    sq += v[j].x * v[j].x + v[j].y * v[j].y + v[j].z * v[j].z + v[j].w * v[j].w;
  }
  for (int off = 32; off; off >>= 1) {
    s += __shfl_xor(s, off, 64);
    sq += __shfl_xor(sq, off, 64);
  }
  float mu = s * (1.0f / DIM);
  float var = sq * (1.0f / DIM) - mu * mu;
  float r = rsqrtf(var + 1e-5f);
  for (int j = 0; j < 4; j++) {
    float4 wv4 = ((const float4*)w)[j * 64 + lane];
    float4 bv4 = ((const float4*)bb)[j * 64 + lane];
    bf16x4 o;
    o[0] = (bf16)((v[j].x - mu) * r * wv4.x + bv4.x);
    o[1] = (bf16)((v[j].y - mu) * r * wv4.y + bv4.y);
    o[2] = (bf16)((v[j].z - mu) * r * wv4.z + bv4.z);
    o[3] = (bf16)((v[j].w - mu) * r * wv4.w + bv4.w);
    *(bf16x4*)(dst + (size_t)row * DIM + (j * 64 + lane) * 4) = o;
  }
}

// ---------------------------------------------------------------------------
// All three weight transposes in one launch: fp32 (1024 x N) -> bf16 (N x 1024)
// ---------------------------------------------------------------------------
__global__ __launch_bounds__(256) void transpose_w_all(
    const float* __restrict__ Wq, const float* __restrict__ Wkv,
    const float* __restrict__ Wout, bf16* __restrict__ WqT,
    bf16* __restrict__ WkvT, bf16* __restrict__ WoutT) {
  __shared__ float tile[32][33];
  int t = blockIdx.x;
  const float* src;
  bf16* dst;
  int N;
  if (t < 1024) { src = Wq; dst = WqT; N = 1024; }
  else if (t < 3072) { t -= 1024; src = Wkv; dst = WkvT; N = 2048; }
  else { t -= 3072; src = Wout; dst = WoutT; N = 1024; }
  int ntiles = N >> 5;
  int n0 = (t % ntiles) * 32, k0 = (t / ntiles) * 32;
  int x = threadIdx.x, y = threadIdx.y;
  for (int j = 0; j < 4; j++)
    tile[y + 8 * j][x] = src[(size_t)(k0 + y + 8 * j) * N + n0 + x];
  __syncthreads();
  for (int j = 0; j < 4; j++)
    dst[(size_t)(n0 + y + 8 * j) * 1024 + k0 + x] = (bf16)tile[x][y + 8 * j];
}

// ---------------------------------------------------------------------------
// GEMM C = A(MxK) @ Bt(NxK)^T, bf16 in, fp32 acc. 128x128 tile, BK=64.
// MODE 0 (kv, grid 16x128): XCD-aware bid remap — each XCD (bid%8) owns a
//   disjoint 16-block m-set, sweeps n with an 8-block m-group L2-resident.
//   n0<1024 -> K half; n0>=1024 -> V half transposed to vt[(b*1024+c)*4096+key]
// MODE 1: AdaLN modulation * attn_scale * log2e, store bf16
// MODE 2: store fp32
// ---------------------------------------------------------------------------
template <int MODE>
__global__ __launch_bounds__(256) void gemm_bf16(
    const bf16* __restrict__ A, const bf16* __restrict__ Bt,
    void* __restrict__ Cout, void* __restrict__ Cout2, int M, int N, int K,
    const float* __restrict__ shiftp, const float* __restrict__ scalep) {
  __shared__ __align__(16) bf16 smem[128 * 64 * 2];  // As | Bs (32KB)
  bf16* As = smem;
  bf16* Bs = smem + 128 * 64;
  int tid = threadIdx.x;
  int lane = tid & 63, wv = tid >> 6;
  int wr = wv >> 1, wc = wv & 1;
  int quad = lane >> 4, lr = lane & 15;
  int m0, n0;
  if (MODE == 0) {
    int bid = blockIdx.y * 16 + blockIdx.x;  // 0..2047
    int c = bid & 7, g = bid >> 3;
    int mi = g & 7, nb = (g >> 3) & 15, chunk = g >> 7;
    m0 = (chunk * 64 + mi * 8 + c) * 128;
    n0 = nb * 128;
  } else {
    m0 = blockIdx.y * 128;
    n0 = blockIdx.x * 128;
  }
  f32x4 acc[4][4] = {};
  for (int kt = 0; kt < K; kt += 64) {
    __syncthreads();
    for (int j = 0; j < 4; j++) {
      int idx0 = j * 256 + wv * 64;  // wave-uniform chunk base
      int row = (idx0 >> 3) + (lane >> 3);
      int cb = (lane & 7) ^ (row & 7);  // global col-block for phys blk lane&7
      async16(&A[(size_t)(m0 + row) * K + kt + cb * 8], &As[idx0 * 8]);
      async16(&Bt[(size_t)(n0 + row) * K + kt + cb * 8], &Bs[idx0 * 8]);
    }
    __syncthreads();
    for (int kk = 0; kk < 2; kk++) {
      bf16x8 af[4], bfr[4];
      for (int im = 0; im < 4; im++) {
        int row = wr * 64 + im * 16 + lr;
        af[im] = *(const bf16x8*)&As[row * 64 + ((quad + 4 * kk) ^ (row & 7)) * 8];
      }
      for (int in = 0; in < 4; in++) {
        int row = wc * 64 + in * 16 + lr;
        bfr[in] = *(const bf16x8*)&Bs[row * 64 + ((quad + 4 * kk) ^ (row & 7)) * 8];
      }
      for (int im = 0; im < 4; im++)
        for (int in = 0; in < 4; in++)
          acc[im][in] = __builtin_amdgcn_mfma_f32_16x16x32_bf16(
              af[im], bfr[in], acc[im][in], 0, 0, 0);
    }
  }

  if (MODE == 0 && n0 >= 1024) {
    // V half: transpose through LDS, write V^T with b128 stores
    bf16* Ct = smem;  // 64 x 136 pitch (17KB)
    for (int pass = 0; pass < 2; pass++) {
      __syncthreads();
      for (int inL = 0; inL < 2; inL++) {
        int in = pass * 2 + inL;
        int cc = wc * 32 + inL * 16 + lr;
        for (int im = 0; im < 4; im++) {
          int rb = wr * 64 + im * 16 + quad * 4;
          bf16x4 pk;
          for (int r = 0; r < 4; r++) pk[r] = (bf16)acc[im][in][r];
          *(bf16x4*)&Ct[cc * 136 + rb] = pk;
        }
      }
      __syncthreads();
      for (int k2 = 0; k2 < 4; k2++) {
        int ci = k2 * 256 + tid;
        int cc = ci >> 4, ch = ci & 15;
        uint4 val = *(const uint4*)&Ct[cc * 136 + ch * 8];
        int gco = (cc >> 5) * 64 + pass * 32 + (cc & 31);
        int col = n0 - 1024 + gco;  // 0..1023 within inner dim
        int bb2 = m0 >> 12;         // batch
        int key = (m0 & 4095) + ch * 8;
        *(uint4*)&((bf16*)Cout2)[((size_t)(bb2 * 1024 + col)) * 4096 + key] = val;
      }
    }
    return;
  }

  for (int im = 0; im < 4; im++)
    for (int in = 0; in < 4; in++) {
      int col = n0 + wc * 64 + in * 16 + lr;
      for (int r = 0; r < 4; r++) {
        int row = m0 + wr * 64 + im * 16 + quad * 4 + r;
        float v = acc[im][in][r];
        if (MODE == 0) {
          ((bf16*)Cout)[(size_t)row * 1024 + col] = (bf16)v;
        } else if (MODE == 1) {
          int bb = row >> 8, hh = col >> 6;
          float sc = scalep[bb * 16 + hh], sh = shiftp[bb * 16 + hh];
          // fold attn_scale (0.125) AND log2(e) so softmax uses exp2
          ((bf16*)Cout)[(size_t)row * N + col] =
              (bf16)((v * (1.0f + sc) + sh) * 0.18033688011112042f);
        } else {
          ((float*)Cout)[(size_t)row * N + col] = v;
        }
      }
    }
}

// ---------------------------------------------------------------------------
// Flash attention v2: block = (b, h, split) -> 256 blocks, 1/CU.
// Each wave owns 64 queries (4 groups of 16); K/V fragments loaded once per
// 64-key tile and reused across all 4 q-groups. K/V double-buffered with
// async global->LDS + raw s_barrier + partial vmcnt (prefetch in flight).
// S^T = K·Q^T (lane owns one query per group: scalar m/l, 2-shuffle reduce).
// ---------------------------------------------------------------------------
__global__ __launch_bounds__(256) void attn_kernel(const bf16* __restrict__ q,
                                                   const bf16* __restrict__ kb,
                                                   const bf16* __restrict__ vt,
                                                   float* __restrict__ opA,
                                                   float* __restrict__ opB,
                                                   float* __restrict__ ml) {
  int b = blockIdx.z, h = blockIdx.y, sp = blockIdx.x;
  int tid = threadIdx.x, lane = tid & 63, wv = tid >> 6;
  int quad = lane >> 4, lr = lane & 15;
  __shared__ __align__(16) bf16 KV[2][2][64 * 64];  // [buf][K|V] 32KB
  __shared__ __align__(16) bf16 QP[4][64 * 64];     // per-wave Q then P (32KB)
  __shared__ float abuf[4][16];

  const bf16* kg = kb + (size_t)(b * N1) * 1024 + h * DH;
  const bf16* vg = vt + (size_t)((b * HEADS + h) * DH) * N1;
  bf16* Qw = QP[wv];
  int srow = lane >> 3, sblk = lane & 7;

  // stage this wave's 64 Q rows (8 async16)
  const bf16* qg = q + (size_t)(b * N2 + wv * 64) * INNER + h * DH;
  for (int j = 0; j < 8; j++) {
    int r = j * 8 + srow;
    async16(&qg[(size_t)r * INNER + (sblk ^ (r & 7)) * 8], &Qw[j * 512]);
  }
  // stage K/V tile 0 into buf 0 (4 async16: this wave's 16 rows of each)
  {
    int key0 = sp * KEYS_PER_SPLIT;
    for (int j = 0; j < 2; j++) {
      int r = wv * 16 + j * 8 + srow;
      async16(&kg[(size_t)(key0 + r) * 1024 + (sblk ^ (r & 7)) * 8],
              &KV[0][0][(wv * 16 + j * 8) * 64]);
      async16(&vg[(size_t)r * N1 + key0 + (sblk ^ (r & 7)) * 8],
              &KV[0][1][(wv * 16 + j * 8) * 64]);
    }
  }
  WAIT_VMCNT_4();  // Q retired (tile0's 4 may remain in flight)
  bf16x8 aQ[4][2];
  for (int g = 0; g < 4; g++) {
    int row = g * 16 + lr;
    for (int kk = 0; kk < 2; kk++)
      aQ[g][kk] = *(const bf16x8*)&Qw[row * 64 + ((quad + 4 * kk) ^ (row & 7)) * 8];
  }
  float m_s[4], l_s[4];
  f32x4 oacc[4][4] = {};
  for (int g = 0; g < 4; g++) { m_s[g] = -1e30f; l_s[g] = 0.0f; }

  for (int t = 0; t < KEYS_PER_SPLIT / 64; t++) {
    if (t + 1 < KEYS_PER_SPLIT / 64) {  // prefetch next tile
      int key0 = sp * KEYS_PER_SPLIT + (t + 1) * 64;
      int d = (t + 1) & 1;
      for (int j = 0; j < 2; j++) {
        int r = wv * 16 + j * 8 + srow;
        async16(&kg[(size_t)(key0 + r) * 1024 + (sblk ^ (r & 7)) * 8],
                &KV[d][0][(wv * 16 + j * 8) * 64]);
        async16(&vg[(size_t)r * N1 + key0 + (sblk ^ (r & 7)) * 8],
                &KV[d][1][(wv * 16 + j * 8) * 64]);
      }
      WAIT_VMCNT_4();  // tile t retired; t+1 still in flight
    } else {
      WAIT_VMCNT_0();
    }
    HW_BARRIER();  // tile t visible to all waves

    const bf16* Ks = KV[t & 1][0];
    const bf16* Vs = KV[t & 1][1];
    bf16x8 ak[2][4], bvf[2][4];
    for (int kk = 0; kk < 2; kk++)
      for (int nt = 0; nt < 4; nt++) {
        int row = nt * 16 + lr;
        ak[kk][nt] =
            *(const bf16x8*)&Ks[row * 64 + ((quad + 4 * kk) ^ (row & 7)) * 8];
        bvf[kk][nt] =
            *(const bf16x8*)&Vs[row * 64 + ((quad + 4 * kk) ^ (row & 7)) * 8];
      }

    bf16* Ps = Qw;  // reuse per-wave Q region as P scratch
    for (int g = 0; g < 4; g++) {
      f32x4 s[4] = {};
      for (int kk = 0; kk < 2; kk++)
        for (int nt = 0; nt < 4; nt++)
          s[nt] = __builtin_amdgcn_mfma_f32_16x16x32_bf16(ak[kk][nt], aQ[g][kk],
                                                          s[nt], 0, 0, 0);
      // per-lane softmax for query = g*16+lr (16 keys in regs, reduce quads)
      float mx = s[0][0];
      for (int nt = 0; nt < 4; nt++)
        for (int r = 0; r < 4; r++) mx = fmaxf(mx, s[nt][r]);
      mx = fmaxf(mx, __shfl_xor(mx, 16, 64));
      mx = fmaxf(mx, __shfl_xor(mx, 32, 64));
      float mn = fmaxf(m_s[g], mx);
      float al = exp2f(m_s[g] - mn);
      float p[4][4], sum = 0.0f;
      for (int nt = 0; nt < 4; nt++)
        for (int r = 0; r < 4; r++) {
          p[nt][r] = exp2f(s[nt][r] - mn);
          sum += p[nt][r];
        }
      sum += __shfl_xor(sum, 16, 64);
      sum += __shfl_xor(sum, 32, 64);
      l_s[g] = l_s[g] * al + sum;
      m_s[g] = mn;
      if (quad == 0) abuf[wv][lr] = al;

      // packed P writes: P[query=lr][key=16nt+4quad+r]
      for (int nt = 0; nt < 4; nt++) {
        bf16x4 pk;
        for (int r = 0; r < 4; r++) pk[r] = (bf16)p[nt][r];
        *(bf16x4*)&Ps[lr * 64 + ((2 * nt + (quad >> 1)) ^ (lr & 7)) * 8 +
                      (quad & 1) * 4] = pk;
      }
      f32x4 a4 = *(const f32x4*)&abuf[wv][quad * 4];
      for (int in = 0; in < 4; in++)
        for (int r = 0; r < 4; r++) oacc[g][in][r] *= a4[r];

      bf16x8 aP[2];
      for (int kk = 0; kk < 2; kk++)
        aP[kk] = *(const bf16x8*)&Ps[lr * 64 + ((4 * kk + quad) ^ (lr & 7)) * 8];
      for (int kk = 0; kk < 2; kk++)
        for (int in = 0; in < 4; in++)
          oacc[g][in] = __builtin_amdgcn_mfma_f32_16x16x32_bf16(
              aP[kk], bvf[kk][in], oacc[g][in], 0, 0, 0);
    }
    HW_BARRIER();  // all waves done reading buf t&1 before it's restaged
  }

  float* ob = (sp < 2 ? opA : opB) + (size_t)(sp & 1) * SPLIT_ELEMS;
  size_t rbase = (size_t)(b * HEADS + h) * N2;
  for (int g = 0; g < 4; g++)
    for (int r = 0; r < 4; r++) {
      int qq = wv * 64 + g * 16 + quad * 4 + r;
      for (int in = 0; in < 4; in++)
        ob[(rbase + qq) * 64 + in * 16 + lr] = oacc[g][in][r];
    }
  if (quad == 0)
    for (int g = 0; g < 4; g++) {
      int qq = wv * 64 + g * 16 + lr;
      float* mlp = ml + ((size_t)sp * (4 * HEADS * N2) + rbase + qq) * 2;
      mlp[0] = m_s[g];
      mlp[1] = l_s[g];
    }
}

// ---------------------------------------------------------------------------
// Combine split-K partials: out = sum_s w_s O_s / sum_s w_s l_s, w_s=2^(m_s-M)
// ---------------------------------------------------------------------------
__global__ __launch_bounds__(256) void combine_kernel(const float* __restrict__ opA,
                                                      const float* __restrict__ opB,
                                                      const float* __restrict__ ml,
                                                      bf16* __restrict__ out) {
  int gid = blockIdx.x * 256 + threadIdx.x;
  int d = gid & 63;
  int rq = gid >> 6;  // (b*16+h)*256 + q
  int qq = rq & 255, bh = rq >> 8;
  int h = bh & 15, b = bh >> 4;
  float m[ASPLIT], l[ASPLIT];
  for (int s = 0; s < ASPLIT; s++) {
    const float* p = ml + ((size_t)s * (4 * HEADS * N2) + rq) * 2;
    m[s] = p[0];
    l[s] = p[1];
  }
  float M = fmaxf(fmaxf(m[0], m[1]), fmaxf(m[2], m[3]));
  float L = 0.0f, o = 0.0f;
  for (int s = 0; s < ASPLIT; s++) {
    float w = exp2f(m[s] - M);
    L += w * l[s];
    const float* op = (s < 2 ? opA : opB) + (size_t)(s & 1) * SPLIT_ELEMS;
    o += w * op[(size_t)rq * 64 + d];
  }
  out[((size_t)(b * N2 + qq)) * INNER + h * DH + d] = (bf16)(o / L);
}

// ---------------------------------------------------------------------------
extern "C" void kernel_launch(void* const* d_in, const int* in_sizes, int n_in,
                              void* d_out, int out_size, void* d_ws,
                              size_t ws_size, hipStream_t stream) {
  const float* x       = (const float*)d_in[0];
  const float* latents = (const float*)d_in[1];
  const float* shift   = (const float*)d_in[2];
  const float* scale   = (const float*)d_in[3];
  const float* ln1w    = (const float*)d_in[4];
  const float* ln1b    = (const float*)d_in[5];
  const float* ln2w    = (const float*)d_in[6];
  const float* ln2b    = (const float*)d_in[7];
  const float* Wq      = (const float*)d_in[8];
  const float* Wkv     = (const float*)d_in[9];
  const float* Wout    = (const float*)d_in[10];

  char* ws = (char*)d_ws;
  bf16*  xn    = (bf16*)(ws);                // 33.5MB; dead after kv gemm
  float* opA   = (float*)(ws);               //   overlay: splits 0,1 partials
  bf16*  lnl   = (bf16*)(ws + 33554432);     // 2MB; dead after q gemm
  float* ml    = (float*)(ws + 33554432);    //   overlay: (m,l) 0.5MB
  bf16*  qb    = (bf16*)(ws + 35651584);     // 2MB
  bf16*  kb    = (bf16*)(ws + 37748736);     // 33.5MB (K half)
  float* opB   = (float*)(ws + 71303168);    // 33.5MB: splits 2,3 partials
  bf16*  vtb   = (bf16*)(ws + 104857600);    // 33.5MB (V^T, written by kv gemm)
  bf16*  aob   = (bf16*)(ws + 138412032);    // 2MB
  bf16*  WqT   = (bf16*)(ws + 140509184);    // 2MB
  bf16*  WkvT  = (bf16*)(ws + 142606336);    // 4MB
  bf16*  WoutT = (bf16*)(ws + 146800640);    // 2MB -> total 148.9MB

  transpose_w_all<<<4096, dim3(32, 8), 0, stream>>>(Wq, Wkv, Wout, WqT, WkvT,
                                                    WoutT);
  ln_kernel<<<4096, 256, 0, stream>>>(x, ln1w, ln1b, xn);
  ln_kernel<<<256, 256, 0, stream>>>(latents, ln2w, ln2b, lnl);

  gemm_bf16<0><<<dim3(16, 128), 256, 0, stream>>>(xn, WkvT, kb, vtb, 16384,
                                                  2048, 1024, nullptr, nullptr);
  gemm_bf16<1><<<dim3(8, 8), 256, 0, stream>>>(lnl, WqT, qb, nullptr, 1024,
                                               1024, 1024, shift, scale);
  attn_kernel<<<dim3(ASPLIT, 16, 4), 256, 0, stream>>>(qb, kb, vtb, opA, opB,
                                                       ml);
  combine_kernel<<<16384, 256, 0, stream>>>(opA, opB, ml, aob);
  gemm_bf16<2><<<dim3(8, 8), 256, 0, stream>>>(aob, WoutT, d_out, nullptr,
                                               1024, 1024, 1024, nullptr, nullptr);
}

// Round 6
// 298.983 us; speedup vs baseline: 1.0925x; 1.0925x over previous
//
#include <hip/hip_runtime.h>

typedef __bf16 bf16;
typedef bf16 bf16x8 __attribute__((ext_vector_type(8)));
typedef bf16 bf16x4 __attribute__((ext_vector_type(4)));
typedef float f32x4 __attribute__((ext_vector_type(4)));

#define B_ 4
#define N1 4096
#define N2 256
#define DIM 1024
#define HEADS 16
#define DH 64
#define INNER 1024
#define ASPLIT 4
#define KEYS_PER_SPLIT (N1 / ASPLIT)     // 1024
#define SPLIT_ELEMS (4 * 16 * 256 * 64)  // fp32 elems per split partial

// async global->LDS, 16B per lane; LDS dest = wave-uniform base + lane*16
typedef __attribute__((address_space(1))) const void gvoid_t;
typedef __attribute__((address_space(3))) void lvoid_t;
__device__ __forceinline__ void async16(const void* g, void* l) {
  __builtin_amdgcn_global_load_lds((gvoid_t*)g, (lvoid_t*)l, 16, 0, 0);
}

// ---------------------------------------------------------------------------
// LayerNorm, both tensors in one launch: fp32 (rows x 1024) -> bf16.
// One WAVE per row (no LDS, no barrier). rows [0,16384) = x, rest = latents.
// grid = 16384/4 + 1024/4 = 4352 blocks  (round-5 bug: 4160 left 768 latent
// rows unnormalized -> absmax 1.06; arithmetic must be 4096 + 256)
// ---------------------------------------------------------------------------
__global__ __launch_bounds__(256) void ln_all(
    const float* __restrict__ x, const float* __restrict__ latents,
    const float* __restrict__ ln1w, const float* __restrict__ ln1b,
    const float* __restrict__ ln2w, const float* __restrict__ ln2b,
    bf16* __restrict__ xn, bf16* __restrict__ lnl) {
  int wv = threadIdx.x >> 6, lane = threadIdx.x & 63;
  int grow = blockIdx.x * 4 + wv;
  const float *src, *w, *bb;
  bf16* dst;
  int row;
  if (grow < 16384) { src = x; w = ln1w; bb = ln1b; dst = xn; row = grow; }
  else { src = latents; w = ln2w; bb = ln2b; dst = lnl; row = grow - 16384; }
  const float4* p = (const float4*)(src + (size_t)row * DIM);
  float4 v[4];
  for (int j = 0; j < 4; j++) v[j] = p[j * 64 + lane];
  float s = 0.f, sq = 0.f;
  for (int j = 0; j < 4; j++) {
    s += v[j].x + v[j].y + v[j].z + v[j].w;
    sq += v[j].x * v[j].x + v[j].y * v[j].y + v[j].z * v[j].z + v[j].w * v[j].w;
  }
  for (int off = 32; off; off >>= 1) {
    s += __shfl_xor(s, off, 64);
    sq += __shfl_xor(sq, off, 64);
  }
  float mu = s * (1.0f / DIM);
  float var = sq * (1.0f / DIM) - mu * mu;
  float r = rsqrtf(var + 1e-5f);
  for (int j = 0; j < 4; j++) {
    float4 wv4 = ((const float4*)w)[j * 64 + lane];
    float4 bv4 = ((const float4*)bb)[j * 64 + lane];
    bf16x4 o;
    o[0] = (bf16)((v[j].x - mu) * r * wv4.x + bv4.x);
    o[1] = (bf16)((v[j].y - mu) * r * wv4.y + bv4.y);
    o[2] = (bf16)((v[j].z - mu) * r * wv4.z + bv4.z);
    o[3] = (bf16)((v[j].w - mu) * r * wv4.w + bv4.w);
    *(bf16x4*)(dst + (size_t)row * DIM + (j * 64 + lane) * 4) = o;
  }
}

// ---------------------------------------------------------------------------
// All three weight transposes in one launch: fp32 (1024 x N) -> bf16 (N x 1024)
// ---------------------------------------------------------------------------
__global__ __launch_bounds__(256) void transpose_w_all(
    const float* __restrict__ Wq, const float* __restrict__ Wkv,
    const float* __restrict__ Wout, bf16* __restrict__ WqT,
    bf16* __restrict__ WkvT, bf16* __restrict__ WoutT) {
  __shared__ float tile[32][33];
  int t = blockIdx.x;
  const float* src;
  bf16* dst;
  int N;
  if (t < 1024) { src = Wq; dst = WqT; N = 1024; }
  else if (t < 3072) { t -= 1024; src = Wkv; dst = WkvT; N = 2048; }
  else { t -= 3072; src = Wout; dst = WoutT; N = 1024; }
  int ntiles = N >> 5;
  int n0 = (t % ntiles) * 32, k0 = (t / ntiles) * 32;
  int x = threadIdx.x, y = threadIdx.y;
  for (int j = 0; j < 4; j++)
    tile[y + 8 * j][x] = src[(size_t)(k0 + y + 8 * j) * N + n0 + x];
  __syncthreads();
  for (int j = 0; j < 4; j++)
    dst[(size_t)(n0 + y + 8 * j) * 1024 + k0 + x] = (bf16)tile[x][y + 8 * j];
}

// ---------------------------------------------------------------------------
// Big GEMM (kv only): C = A(MxK) @ Bt(NxK)^T, 128x128 tile, BK=64.
// XCD-aware bid remap: each XCD (bid%8) owns a disjoint m-set, sweeps n with
// an 8-block m-group L2-resident.
// n0<1024 -> K half (bf16, stride 1024); n0>=1024 -> V half transposed to
// vt[(b*1024+c)*4096+key].
// ---------------------------------------------------------------------------
__global__ __launch_bounds__(256) void gemm_kv(
    const bf16* __restrict__ A, const bf16* __restrict__ Bt,
    bf16* __restrict__ Cout, bf16* __restrict__ Cout2, int K) {
  __shared__ __align__(16) bf16 smem[128 * 64 * 2];  // As | Bs (32KB)
  bf16* As = smem;
  bf16* Bs = smem + 128 * 64;
  int tid = threadIdx.x;
  int lane = tid & 63, wv = tid >> 6;
  int wr = wv >> 1, wc = wv & 1;
  int quad = lane >> 4, lr = lane & 15;
  int bid = blockIdx.y * 16 + blockIdx.x;  // 0..2047
  int c = bid & 7, g = bid >> 3;
  int mi = g & 7, nb = (g >> 3) & 15, chunk = g >> 7;
  int m0 = (chunk * 64 + mi * 8 + c) * 128;
  int n0 = nb * 128;
  f32x4 acc[4][4] = {};
  for (int kt = 0; kt < K; kt += 64) {
    __syncthreads();
    for (int j = 0; j < 4; j++) {
      int idx0 = j * 256 + wv * 64;  // wave-uniform chunk base
      int row = (idx0 >> 3) + (lane >> 3);
      int cb = (lane & 7) ^ (row & 7);  // global col-block for phys blk lane&7
      async16(&A[(size_t)(m0 + row) * K + kt + cb * 8], &As[idx0 * 8]);
      async16(&Bt[(size_t)(n0 + row) * K + kt + cb * 8], &Bs[idx0 * 8]);
    }
    __syncthreads();
    for (int kk = 0; kk < 2; kk++) {
      bf16x8 af[4], bfr[4];
      for (int im = 0; im < 4; im++) {
        int row = wr * 64 + im * 16 + lr;
        af[im] = *(const bf16x8*)&As[row * 64 + ((quad + 4 * kk) ^ (row & 7)) * 8];
      }
      for (int in = 0; in < 4; in++) {
        int row = wc * 64 + in * 16 + lr;
        bfr[in] = *(const bf16x8*)&Bs[row * 64 + ((quad + 4 * kk) ^ (row & 7)) * 8];
      }
      for (int im = 0; im < 4; im++)
        for (int in = 0; in < 4; in++)
          acc[im][in] = __builtin_amdgcn_mfma_f32_16x16x32_bf16(
              af[im], bfr[in], acc[im][in], 0, 0, 0);
    }
  }

  if (n0 >= 1024) {
    // V half: transpose through LDS, write V^T with b128 stores
    bf16* Ct = smem;  // 64 x 136 pitch (17KB)
    for (int pass = 0; pass < 2; pass++) {
      __syncthreads();
      for (int inL = 0; inL < 2; inL++) {
        int in = pass * 2 + inL;
        int cc = wc * 32 + inL * 16 + lr;
        for (int im = 0; im < 4; im++) {
          int rb = wr * 64 + im * 16 + quad * 4;
          bf16x4 pk;
          for (int r = 0; r < 4; r++) pk[r] = (bf16)acc[im][in][r];
          *(bf16x4*)&Ct[cc * 136 + rb] = pk;
        }
      }
      __syncthreads();
      for (int k2 = 0; k2 < 4; k2++) {
        int ci = k2 * 256 + tid;
        int cc = ci >> 4, ch = ci & 15;
        uint4 val = *(const uint4*)&Ct[cc * 136 + ch * 8];
        int gco = (cc >> 5) * 64 + pass * 32 + (cc & 31);
        int col = n0 - 1024 + gco;  // 0..1023 within inner dim
        int bb2 = m0 >> 12;         // batch
        int key = (m0 & 4095) + ch * 8;
        *(uint4*)&Cout2[((size_t)(bb2 * 1024 + col)) * 4096 + key] = val;
      }
    }
    return;
  }

  for (int im = 0; im < 4; im++)
    for (int in = 0; in < 4; in++) {
      int col = n0 + wc * 64 + in * 16 + lr;
      for (int r = 0; r < 4; r++) {
        int row = m0 + wr * 64 + im * 16 + quad * 4 + r;
        Cout[(size_t)row * 1024 + col] = (bf16)acc[im][in][r];
      }
    }
}

// ---------------------------------------------------------------------------
// Small GEMM: 64x64 tile, BK=64, full-chip grids for the 1024^3 GEMMs.
// MODE 1: AdaLN modulation * attn_scale * log2e, store bf16
// MODE 2: store fp32
// ---------------------------------------------------------------------------
template <int MODE>
__global__ __launch_bounds__(256) void gemm64(
    const bf16* __restrict__ A, const bf16* __restrict__ Bt,
    void* __restrict__ Cout, int K, int N,
    const float* __restrict__ shiftp, const float* __restrict__ scalep) {
  __shared__ __align__(16) bf16 As[64 * 64];
  __shared__ __align__(16) bf16 Bs[64 * 64];
  int tid = threadIdx.x;
  int lane = tid & 63, wv = tid >> 6;
  int wr = wv >> 1, wc = wv & 1;
  int quad = lane >> 4, lr = lane & 15;
  int m0 = blockIdx.y * 64, n0 = blockIdx.x * 64;
  f32x4 acc[2][2] = {};
  for (int kt = 0; kt < K; kt += 64) {
    __syncthreads();
    for (int j = 0; j < 2; j++) {
      int idx0 = j * 256 + wv * 64;  // wave-uniform chunk base (512 chunks)
      int row = (idx0 >> 3) + (lane >> 3);
      int cb = (lane & 7) ^ (row & 7);
      async16(&A[(size_t)(m0 + row) * K + kt + cb * 8], &As[idx0 * 8]);
      async16(&Bt[(size_t)(n0 + row) * K + kt + cb * 8], &Bs[idx0 * 8]);
    }
    __syncthreads();
    for (int kk = 0; kk < 2; kk++) {
      bf16x8 af[2], bfr[2];
      for (int im = 0; im < 2; im++) {
        int row = wr * 32 + im * 16 + lr;
        af[im] = *(const bf16x8*)&As[row * 64 + ((quad + 4 * kk) ^ (row & 7)) * 8];
      }
      for (int in = 0; in < 2; in++) {
        int row = wc * 32 + in * 16 + lr;
        bfr[in] = *(const bf16x8*)&Bs[row * 64 + ((quad + 4 * kk) ^ (row & 7)) * 8];
      }
      for (int im = 0; im < 2; im++)
        for (int in = 0; in < 2; in++)
          acc[im][in] = __builtin_amdgcn_mfma_f32_16x16x32_bf16(
              af[im], bfr[in], acc[im][in], 0, 0, 0);
    }
  }
  for (int im = 0; im < 2; im++)
    for (int in = 0; in < 2; in++) {
      int col = n0 + wc * 32 + in * 16 + lr;
      for (int r = 0; r < 4; r++) {
        int row = m0 + wr * 32 + im * 16 + quad * 4 + r;
        float v = acc[im][in][r];
        if (MODE == 1) {
          int bb = row >> 8, hh = col >> 6;
          float sc = scalep[bb * 16 + hh], sh = shiftp[bb * 16 + hh];
          // fold attn_scale (0.125) AND log2(e) so softmax uses exp2
          ((bf16*)Cout)[(size_t)row * N + col] =
              (bf16)((v * (1.0f + sc) + sh) * 0.18033688011112042f);
        } else {
          ((float*)Cout)[(size_t)row * N + col] = v;
        }
      }
    }
}

// ---------------------------------------------------------------------------
// Flash attention (round-3 proven version), split-K over keys.
// block = (b, h, qtile, split); 4 waves x 16 queries each; 16 waves/CU.
// S^T = K·Q^T: lane owns one query (col), 4 consecutive keys per C-reg ->
// scalar m/l, 2-shuffle reductions, packed b64 P writes. log2-domain softmax.
// ---------------------------------------------------------------------------
__global__ __launch_bounds__(256) void attn_kernel(const bf16* __restrict__ q,
                                                   const bf16* __restrict__ kb,
                                                   const bf16* __restrict__ vt,
                                                   float* __restrict__ opA,
                                                   float* __restrict__ opB,
                                                   float* __restrict__ ml) {
  int b = blockIdx.z, h = blockIdx.y;
  int qt = blockIdx.x >> 2, sp = blockIdx.x & 3;  // sp in low bits: qt-siblings
  int tid = threadIdx.x, lane = tid & 63, wv = tid >> 6;  // nearer in XCD space
  int quad = lane >> 4, lr = lane & 15;
  __shared__ __align__(16) bf16 Ks[64 * 64];
  __shared__ __align__(16) bf16 Vs[64 * 64];  // [dh][key]
  __shared__ __align__(16) bf16 QP[64 * 64];  // Q tile, then per-wave P scratch
  __shared__ float abuf[4][16];
  int q0 = qt * 64;

  const bf16* qg = q + (size_t)(b * N2 + q0) * INNER + h * DH;
  for (int j = 0; j < 2; j++) {
    int r0 = j * 32 + wv * 8;
    int r = r0 + (lane >> 3);
    async16(&qg[(size_t)r * INNER + ((lane & 7) ^ (r & 7)) * 8], &QP[r0 * 64]);
  }
  __syncthreads();
  bf16x8 aQ[2];
  {
    int row = wv * 16 + lr;
    for (int kk = 0; kk < 2; kk++)
      aQ[kk] = *(const bf16x8*)&QP[row * 64 + ((quad + 4 * kk) ^ (row & 7)) * 8];
  }
  float m_s = -1e30f, l_s = 0.0f;
  f32x4 oacc[4] = {};

  const bf16* kg = kb + (size_t)(b * N1) * 1024 + h * DH;
  const bf16* vg = vt + (size_t)((b * HEADS + h) * DH) * N1;
  bf16* Ps = QP + wv * 1024;  // wave-private 16 x 64

  for (int t = 0; t < KEYS_PER_SPLIT / 64; t++) {
    int key0 = sp * KEYS_PER_SPLIT + t * 64;
    __syncthreads();
    for (int j = 0; j < 2; j++) {
      int r0 = j * 32 + wv * 8;
      int r = r0 + (lane >> 3);
      int cs = ((lane & 7) ^ (r & 7)) * 8;
      async16(&kg[(size_t)(key0 + r) * 1024 + cs], &Ks[r0 * 64]);
      async16(&vg[(size_t)r * N1 + key0 + cs], &Vs[r0 * 64]);
    }
    __syncthreads();

    // S^T tiles: rows = keys (quad*4+r within 16nt), cols = queries (lr)
    f32x4 s[4] = {};
    for (int kk = 0; kk < 2; kk++)
      for (int nt = 0; nt < 4; nt++) {
        int row = nt * 16 + lr;
        bf16x8 ak =
            *(const bf16x8*)&Ks[row * 64 + ((quad + 4 * kk) ^ (row & 7)) * 8];
        s[nt] = __builtin_amdgcn_mfma_f32_16x16x32_bf16(ak, aQ[kk], s[nt], 0, 0, 0);
      }

    // per-lane softmax for query = lr (16 keys in regs, reduce across quads)
    float mx = s[0][0];
    for (int nt = 0; nt < 4; nt++)
      for (int r = 0; r < 4; r++) mx = fmaxf(mx, s[nt][r]);
    mx = fmaxf(mx, __shfl_xor(mx, 16, 64));
    mx = fmaxf(mx, __shfl_xor(mx, 32, 64));
    float mn = fmaxf(m_s, mx);
    float al = exp2f(m_s - mn);
    float p[4][4], sum = 0.0f;
    for (int nt = 0; nt < 4; nt++)
      for (int r = 0; r < 4; r++) {
        p[nt][r] = exp2f(s[nt][r] - mn);
        sum += p[nt][r];
      }
    sum += __shfl_xor(sum, 16, 64);
    sum += __shfl_xor(sum, 32, 64);
    l_s = l_s * al + sum;
    m_s = mn;
    if (quad == 0) abuf[wv][lr] = al;

    // packed P writes: P[query=lr][key=16nt+4quad+r], r=0..3 contiguous
    for (int nt = 0; nt < 4; nt++) {
      bf16x4 pk;
      for (int r = 0; r < 4; r++) pk[r] = (bf16)p[nt][r];
      *(bf16x4*)&Ps[lr * 64 + ((2 * nt + (quad >> 1)) ^ (lr & 7)) * 8 +
                    (quad & 1) * 4] = pk;
    }

    // rescale O accumulator (rows = query = quad*4+r)
    f32x4 a4 = *(const f32x4*)&abuf[wv][quad * 4];
    for (int in = 0; in < 4; in++)
      for (int r = 0; r < 4; r++) oacc[in][r] *= a4[r];

    bf16x8 aP[2];
    for (int kk = 0; kk < 2; kk++)
      aP[kk] = *(const bf16x8*)&Ps[lr * 64 + ((4 * kk + quad) ^ (lr & 7)) * 8];

    for (int kk = 0; kk < 2; kk++)
      for (int in = 0; in < 4; in++) {
        int row = in * 16 + lr;
        bf16x8 bv =
            *(const bf16x8*)&Vs[row * 64 + ((quad + 4 * kk) ^ (row & 7)) * 8];
        oacc[in] = __builtin_amdgcn_mfma_f32_16x16x32_bf16(aP[kk], bv, oacc[in], 0, 0, 0);
      }
  }

  float* ob = (sp < 2 ? opA : opB) + (size_t)(sp & 1) * SPLIT_ELEMS;
  size_t rbase = (size_t)(b * HEADS + h) * N2;
  for (int r = 0; r < 4; r++) {
    int qq = q0 + wv * 16 + quad * 4 + r;
    for (int in = 0; in < 4; in++)
      ob[(rbase + qq) * 64 + in * 16 + lr] = oacc[in][r];
  }
  if (quad == 0) {
    int qq = q0 + wv * 16 + lr;
    float* mlp = ml + ((size_t)sp * (4 * HEADS * N2) + rbase + qq) * 2;
    mlp[0] = m_s;
    mlp[1] = l_s;
  }
}

// ---------------------------------------------------------------------------
// Combine split-K partials: out = sum_s w_s O_s / sum_s w_s l_s, w_s=2^(m_s-M)
// ---------------------------------------------------------------------------
__global__ __launch_bounds__(256) void combine_kernel(const float* __restrict__ opA,
                                                      const float* __restrict__ opB,
                                                      const float* __restrict__ ml,
                                                      bf16* __restrict__ out) {
  int gid = blockIdx.x * 256 + threadIdx.x;
  int d = gid & 63;
  int rq = gid >> 6;  // (b*16+h)*256 + q
  int qq = rq & 255, bh = rq >> 8;
  int h = bh & 15, b = bh >> 4;
  float m[ASPLIT], l[ASPLIT];
  for (int s = 0; s < ASPLIT; s++) {
    const float* p = ml + ((size_t)s * (4 * HEADS * N2) + rq) * 2;
    m[s] = p[0];
    l[s] = p[1];
  }
  float M = fmaxf(fmaxf(m[0], m[1]), fmaxf(m[2], m[3]));
  float L = 0.0f, o = 0.0f;
  for (int s = 0; s < ASPLIT; s++) {
    float w = exp2f(m[s] - M);
    L += w * l[s];
    const float* op = (s < 2 ? opA : opB) + (size_t)(s & 1) * SPLIT_ELEMS;
    o += w * op[(size_t)rq * 64 + d];
  }
  out[((size_t)(b * N2 + qq)) * INNER + h * DH + d] = (bf16)(o / L);
}

// ---------------------------------------------------------------------------
extern "C" void kernel_launch(void* const* d_in, const int* in_sizes, int n_in,
                              void* d_out, int out_size, void* d_ws,
                              size_t ws_size, hipStream_t stream) {
  const float* x       = (const float*)d_in[0];
  const float* latents = (const float*)d_in[1];
  const float* shift   = (const float*)d_in[2];
  const float* scale   = (const float*)d_in[3];
  const float* ln1w    = (const float*)d_in[4];
  const float* ln1b    = (const float*)d_in[5];
  const float* ln2w    = (const float*)d_in[6];
  const float* ln2b    = (const float*)d_in[7];
  const float* Wq      = (const float*)d_in[8];
  const float* Wkv     = (const float*)d_in[9];
  const float* Wout    = (const float*)d_in[10];

  char* ws = (char*)d_ws;
  bf16*  xn    = (bf16*)(ws);                // 33.5MB; dead after kv gemm
  float* opA   = (float*)(ws);               //   overlay: splits 0,1 partials
  bf16*  lnl   = (bf16*)(ws + 33554432);     // 2MB; dead after q gemm
  float* ml    = (float*)(ws + 33554432);    //   overlay: (m,l) 0.5MB
  bf16*  qb    = (bf16*)(ws + 35651584);     // 2MB
  bf16*  kb    = (bf16*)(ws + 37748736);     // 33.5MB (K half)
  float* opB   = (float*)(ws + 71303168);    // 33.5MB: splits 2,3 partials
  bf16*  vtb   = (bf16*)(ws + 104857600);    // 33.5MB (V^T, written by kv gemm)
  bf16*  aob   = (bf16*)(ws + 138412032);    // 2MB
  bf16*  WqT   = (bf16*)(ws + 140509184);    // 2MB
  bf16*  WkvT  = (bf16*)(ws + 142606336);    // 4MB
  bf16*  WoutT = (bf16*)(ws + 146800640);    // 2MB -> total 148.9MB

  transpose_w_all<<<4096, dim3(32, 8), 0, stream>>>(Wq, Wkv, Wout, WqT, WkvT,
                                                    WoutT);
  ln_all<<<4352, 256, 0, stream>>>(x, latents, ln1w, ln1b, ln2w, ln2b, xn, lnl);

  gemm_kv<<<dim3(16, 128), 256, 0, stream>>>(xn, WkvT, kb, vtb, 1024);
  gemm64<1><<<dim3(16, 16), 256, 0, stream>>>(lnl, WqT, qb, 1024, 1024, shift,
                                              scale);
  attn_kernel<<<dim3(4 * ASPLIT, 16, 4), 256, 0, stream>>>(qb, kb, vtb, opA,
                                                           opB, ml);
  combine_kernel<<<16384, 256, 0, stream>>>(opA, opB, ml, aob);
  gemm64<2><<<dim3(16, 16), 256, 0, stream>>>(aob, WoutT, d_out, 1024, 1024,
                                              nullptr, nullptr);
}

// Round 7
// 288.445 us; speedup vs baseline: 1.1324x; 1.0365x over previous
//
#include <hip/hip_runtime.h>

typedef __bf16 bf16;
typedef bf16 bf16x8 __attribute__((ext_vector_type(8)));
typedef bf16 bf16x4 __attribute__((ext_vector_type(4)));
typedef float f32x4 __attribute__((ext_vector_type(4)));

#define B_ 4
#define N1 4096
#define N2 256
#define DIM 1024
#define HEADS 16
#define DH 64
#define INNER 1024
#define ASPLIT 4
#define KEYS_PER_SPLIT (N1 / ASPLIT)      // 1024
#define SPLIT_ELEMS (4 * 16 * 256 * 64)   // elems per split partial (bf16 now)
#define ROWS_TOTAL (4 * HEADS * N2)       // 16384 rows per split

// async global->LDS, 16B per lane; LDS dest = wave-uniform base + lane*16
typedef __attribute__((address_space(1))) const void gvoid_t;
typedef __attribute__((address_space(3))) void lvoid_t;
__device__ __forceinline__ void async16(const void* g, void* l) {
  __builtin_amdgcn_global_load_lds((gvoid_t*)g, (lvoid_t*)l, 16, 0, 0);
}

// ---------------------------------------------------------------------------
// prep: fused weight transposes + both LayerNorms in one launch.
// blocks [0,4096): fp32 (1024 x N) -> bf16 (N x 1024) transpose (Wq/Wkv/Wout)
// blocks [4096,8448): wave-per-row LN (16384 x rows + 1024 latent rows)
// ---------------------------------------------------------------------------
__global__ __launch_bounds__(256) void prep(
    const float* __restrict__ Wq, const float* __restrict__ Wkv,
    const float* __restrict__ Wout, bf16* __restrict__ WqT,
    bf16* __restrict__ WkvT, bf16* __restrict__ WoutT,
    const float* __restrict__ x, const float* __restrict__ latents,
    const float* __restrict__ ln1w, const float* __restrict__ ln1b,
    const float* __restrict__ ln2w, const float* __restrict__ ln2b,
    bf16* __restrict__ xn, bf16* __restrict__ lnl) {
  __shared__ float tile[32][33];
  int t = blockIdx.x;
  if (t < 4096) {  // ---- transpose path ----
    const float* src;
    bf16* dst;
    int N;
    if (t < 1024) { src = Wq; dst = WqT; N = 1024; }
    else if (t < 3072) { t -= 1024; src = Wkv; dst = WkvT; N = 2048; }
    else { t -= 3072; src = Wout; dst = WoutT; N = 1024; }
    int ntiles = N >> 5;
    int n0 = (t % ntiles) * 32, k0 = (t / ntiles) * 32;
    int xx = threadIdx.x & 31, yy = threadIdx.x >> 5;
    for (int j = 0; j < 4; j++)
      tile[yy + 8 * j][xx] = src[(size_t)(k0 + yy + 8 * j) * N + n0 + xx];
    __syncthreads();
    for (int j = 0; j < 4; j++)
      dst[(size_t)(n0 + yy + 8 * j) * 1024 + k0 + xx] = (bf16)tile[xx][yy + 8 * j];
    return;
  }
  // ---- LN path: grid tail = 16384/4 + 1024/4 = 4352 blocks ----
  int wv = threadIdx.x >> 6, lane = threadIdx.x & 63;
  int grow = (t - 4096) * 4 + wv;
  const float *src, *w, *bb;
  bf16* dst;
  int row;
  if (grow < 16384) { src = x; w = ln1w; bb = ln1b; dst = xn; row = grow; }
  else { src = latents; w = ln2w; bb = ln2b; dst = lnl; row = grow - 16384; }
  const float4* p = (const float4*)(src + (size_t)row * DIM);
  float4 v[4];
  for (int j = 0; j < 4; j++) v[j] = p[j * 64 + lane];
  float s = 0.f, sq = 0.f;
  for (int j = 0; j < 4; j++) {
    s += v[j].x + v[j].y + v[j].z + v[j].w;
    sq += v[j].x * v[j].x + v[j].y * v[j].y + v[j].z * v[j].z + v[j].w * v[j].w;
  }
  for (int off = 32; off; off >>= 1) {
    s += __shfl_xor(s, off, 64);
    sq += __shfl_xor(sq, off, 64);
  }
  float mu = s * (1.0f / DIM);
  float var = sq * (1.0f / DIM) - mu * mu;
  float r = rsqrtf(var + 1e-5f);
  for (int j = 0; j < 4; j++) {
    float4 wv4 = ((const float4*)w)[j * 64 + lane];
    float4 bv4 = ((const float4*)bb)[j * 64 + lane];
    bf16x4 o;
    o[0] = (bf16)((v[j].x - mu) * r * wv4.x + bv4.x);
    o[1] = (bf16)((v[j].y - mu) * r * wv4.y + bv4.y);
    o[2] = (bf16)((v[j].z - mu) * r * wv4.z + bv4.z);
    o[3] = (bf16)((v[j].w - mu) * r * wv4.w + bv4.w);
    *(bf16x4*)(dst + (size_t)row * DIM + (j * 64 + lane) * 4) = o;
  }
}

// ---------------------------------------------------------------------------
// Fused big GEMM launch: blocks [0,2048) = kv GEMM (128x128, BK=64,
// XCD-aware swizzle; K half direct, V half LDS-transposed to V^T).
// Blocks [2048,2304) = q GEMM (64x64) with AdaLN epilogue (tail-fill).
// ---------------------------------------------------------------------------
__global__ __launch_bounds__(256) void gemm_kvq(
    const bf16* __restrict__ A, const bf16* __restrict__ Bt,
    bf16* __restrict__ Cout, bf16* __restrict__ Cout2,
    const bf16* __restrict__ Aq, const bf16* __restrict__ Bq,
    bf16* __restrict__ Cq, const float* __restrict__ shiftp,
    const float* __restrict__ scalep) {
  __shared__ __align__(16) bf16 smem[128 * 64 * 2];  // As | Bs (32KB)
  int tid = threadIdx.x;
  int lane = tid & 63, wv = tid >> 6;
  int wr = wv >> 1, wc = wv & 1;
  int quad = lane >> 4, lr = lane & 15;
  int bidx = blockIdx.x;

  if (bidx >= 2048) {  // ---------------- q-GEMM tail path ----------------
    int qbid = bidx - 2048;  // 0..255
    int m0 = (qbid >> 4) * 64, n0 = (qbid & 15) * 64;
    bf16* As = smem;
    bf16* Bs = smem + 64 * 64;
    f32x4 acc[2][2] = {};
    for (int kt = 0; kt < 1024; kt += 64) {
      __syncthreads();
      for (int j = 0; j < 2; j++) {
        int idx0 = j * 256 + wv * 64;
        int row = (idx0 >> 3) + (lane >> 3);
        int cb = (lane & 7) ^ (row & 7);
        async16(&Aq[(size_t)(m0 + row) * 1024 + kt + cb * 8], &As[idx0 * 8]);
        async16(&Bq[(size_t)(n0 + row) * 1024 + kt + cb * 8], &Bs[idx0 * 8]);
      }
      __syncthreads();
      for (int kk = 0; kk < 2; kk++) {
        bf16x8 af[2], bfr[2];
        for (int im = 0; im < 2; im++) {
          int row = wr * 32 + im * 16 + lr;
          af[im] = *(const bf16x8*)&As[row * 64 + ((quad + 4 * kk) ^ (row & 7)) * 8];
        }
        for (int in = 0; in < 2; in++) {
          int row = wc * 32 + in * 16 + lr;
          bfr[in] = *(const bf16x8*)&Bs[row * 64 + ((quad + 4 * kk) ^ (row & 7)) * 8];
        }
        for (int im = 0; im < 2; im++)
          for (int in = 0; in < 2; in++)
            acc[im][in] = __builtin_amdgcn_mfma_f32_16x16x32_bf16(
                af[im], bfr[in], acc[im][in], 0, 0, 0);
      }
    }
    for (int im = 0; im < 2; im++)
      for (int in = 0; in < 2; in++) {
        int col = n0 + wc * 32 + in * 16 + lr;
        for (int r = 0; r < 4; r++) {
          int row = m0 + wr * 32 + im * 16 + quad * 4 + r;
          int bb = row >> 8, hh = col >> 6;
          float sc = scalep[bb * 16 + hh], sh = shiftp[bb * 16 + hh];
          // fold attn_scale (0.125) AND log2(e) so softmax uses exp2
          Cq[(size_t)row * 1024 + col] =
              (bf16)((acc[im][in][r] * (1.0f + sc) + sh) * 0.18033688011112042f);
        }
      }
    return;
  }

  // ---------------- kv path ----------------
  bf16* As = smem;
  bf16* Bs = smem + 128 * 64;
  int c = bidx & 7, g = bidx >> 3;
  int mi = g & 7, nb = (g >> 3) & 15, chunk = g >> 7;
  int m0 = (chunk * 64 + mi * 8 + c) * 128;
  int n0 = nb * 128;
  f32x4 acc[4][4] = {};
  for (int kt = 0; kt < 1024; kt += 64) {
    __syncthreads();
    for (int j = 0; j < 4; j++) {
      int idx0 = j * 256 + wv * 64;
      int row = (idx0 >> 3) + (lane >> 3);
      int cb = (lane & 7) ^ (row & 7);
      async16(&A[(size_t)(m0 + row) * 1024 + kt + cb * 8], &As[idx0 * 8]);
      async16(&Bt[(size_t)(n0 + row) * 1024 + kt + cb * 8], &Bs[idx0 * 8]);
    }
    __syncthreads();
    for (int kk = 0; kk < 2; kk++) {
      bf16x8 af[4], bfr[4];
      for (int im = 0; im < 4; im++) {
        int row = wr * 64 + im * 16 + lr;
        af[im] = *(const bf16x8*)&As[row * 64 + ((quad + 4 * kk) ^ (row & 7)) * 8];
      }
      for (int in = 0; in < 4; in++) {
        int row = wc * 64 + in * 16 + lr;
        bfr[in] = *(const bf16x8*)&Bs[row * 64 + ((quad + 4 * kk) ^ (row & 7)) * 8];
      }
      for (int im = 0; im < 4; im++)
        for (int in = 0; in < 4; in++)
          acc[im][in] = __builtin_amdgcn_mfma_f32_16x16x32_bf16(
              af[im], bfr[in], acc[im][in], 0, 0, 0);
    }
  }

  if (n0 >= 1024) {
    // V half: transpose through LDS, write V^T with b128 stores
    bf16* Ct = smem;  // 64 x 136 pitch
    for (int pass = 0; pass < 2; pass++) {
      __syncthreads();
      for (int inL = 0; inL < 2; inL++) {
        int in = pass * 2 + inL;
        int cc = wc * 32 + inL * 16 + lr;
        for (int im = 0; im < 4; im++) {
          int rb = wr * 64 + im * 16 + quad * 4;
          bf16x4 pk;
          for (int r = 0; r < 4; r++) pk[r] = (bf16)acc[im][in][r];
          *(bf16x4*)&Ct[cc * 136 + rb] = pk;
        }
      }
      __syncthreads();
      for (int k2 = 0; k2 < 4; k2++) {
        int ci = k2 * 256 + tid;
        int cc = ci >> 4, ch = ci & 15;
        uint4 val = *(const uint4*)&Ct[cc * 136 + ch * 8];
        int gco = (cc >> 5) * 64 + pass * 32 + (cc & 31);
        int col = n0 - 1024 + gco;
        int bb2 = m0 >> 12;
        int key = (m0 & 4095) + ch * 8;
        *(uint4*)&Cout2[((size_t)(bb2 * 1024 + col)) * 4096 + key] = val;
      }
    }
    return;
  }

  for (int im = 0; im < 4; im++)
    for (int in = 0; in < 4; in++) {
      int col = n0 + wc * 64 + in * 16 + lr;
      for (int r = 0; r < 4; r++) {
        int row = m0 + wr * 64 + im * 16 + quad * 4 + r;
        Cout[(size_t)row * 1024 + col] = (bf16)acc[im][in][r];
      }
    }
}

// ---------------------------------------------------------------------------
// Small GEMM (out-projection): 64x64 tile, BK=64, store fp32.
// ---------------------------------------------------------------------------
__global__ __launch_bounds__(256) void gemm_out(
    const bf16* __restrict__ A, const bf16* __restrict__ Bt,
    float* __restrict__ Cout) {
  __shared__ __align__(16) bf16 As[64 * 64];
  __shared__ __align__(16) bf16 Bs[64 * 64];
  int tid = threadIdx.x;
  int lane = tid & 63, wv = tid >> 6;
  int wr = wv >> 1, wc = wv & 1;
  int quad = lane >> 4, lr = lane & 15;
  int m0 = blockIdx.y * 64, n0 = blockIdx.x * 64;
  f32x4 acc[2][2] = {};
  for (int kt = 0; kt < 1024; kt += 64) {
    __syncthreads();
    for (int j = 0; j < 2; j++) {
      int idx0 = j * 256 + wv * 64;
      int row = (idx0 >> 3) + (lane >> 3);
      int cb = (lane & 7) ^ (row & 7);
      async16(&A[(size_t)(m0 + row) * 1024 + kt + cb * 8], &As[idx0 * 8]);
      async16(&Bt[(size_t)(n0 + row) * 1024 + kt + cb * 8], &Bs[idx0 * 8]);
    }
    __syncthreads();
    for (int kk = 0; kk < 2; kk++) {
      bf16x8 af[2], bfr[2];
      for (int im = 0; im < 2; im++) {
        int row = wr * 32 + im * 16 + lr;
        af[im] = *(const bf16x8*)&As[row * 64 + ((quad + 4 * kk) ^ (row & 7)) * 8];
      }
      for (int in = 0; in < 2; in++) {
        int row = wc * 32 + in * 16 + lr;
        bfr[in] = *(const bf16x8*)&Bs[row * 64 + ((quad + 4 * kk) ^ (row & 7)) * 8];
      }
      for (int im = 0; im < 2; im++)
        for (int in = 0; in < 2; in++)
          acc[im][in] = __builtin_amdgcn_mfma_f32_16x16x32_bf16(
              af[im], bfr[in], acc[im][in], 0, 0, 0);
    }
  }
  for (int im = 0; im < 2; im++)
    for (int in = 0; in < 2; in++) {
      int col = n0 + wc * 32 + in * 16 + lr;
      for (int r = 0; r < 4; r++) {
        int row = m0 + wr * 32 + im * 16 + quad * 4 + r;
        Cout[(size_t)row * 1024 + col] = acc[im][in][r];
      }
    }
}

// ---------------------------------------------------------------------------
// Flash attention: block = (b, h, 2 q-tiles, split) -> 512 blocks, 2/CU.
// Each wave owns 32 queries (2 groups of 16); K/V fragments hoisted once per
// 64-key tile and reused across both q-groups. S^T = K·Q^T (lane owns one
// query: scalar m/l, 2-shuffle reductions, packed b64 P writes; P scratch
// overlays the wave's OWN Q rows — exclusive, no cross-wave race).
// Outputs: normalized bf16 partial Ô_s and lse_s = m + log2(l).
// ---------------------------------------------------------------------------
__global__ __launch_bounds__(256) void attn_kernel(const bf16* __restrict__ q,
                                                   const bf16* __restrict__ kb,
                                                   const bf16* __restrict__ vt,
                                                   bf16* __restrict__ opb,
                                                   float* __restrict__ lseb) {
  int b = blockIdx.z, h = blockIdx.y;
  int qp = blockIdx.x >> 2, sp = blockIdx.x & 3;
  int tid = threadIdx.x, lane = tid & 63, wv = tid >> 6;
  int quad = lane >> 4, lr = lane & 15;
  __shared__ __align__(16) bf16 Ks[64 * 64];
  __shared__ __align__(16) bf16 Vs[64 * 64];    // [dh][key]
  __shared__ __align__(16) bf16 QP[128 * 64];   // 128 Q rows; P overlays own rows
  __shared__ float abuf[4][16];
  int q0 = qp * 128;

  // stage 128 Q rows (4 async16/thread)
  const bf16* qg = q + (size_t)(b * N2 + q0) * INNER + h * DH;
  for (int j = 0; j < 4; j++) {
    int r0 = j * 32 + wv * 8;
    int r = r0 + (lane >> 3);
    async16(&qg[(size_t)r * INNER + ((lane & 7) ^ (r & 7)) * 8], &QP[r0 * 64]);
  }
  __syncthreads();
  bf16x8 aQ[2][2];
  for (int g = 0; g < 2; g++) {
    int row = wv * 32 + g * 16 + lr;
    for (int kk = 0; kk < 2; kk++)
      aQ[g][kk] = *(const bf16x8*)&QP[row * 64 + ((quad + 4 * kk) ^ (row & 7)) * 8];
  }
  float m_s[2] = {-1e30f, -1e30f}, l_s[2] = {0.0f, 0.0f};
  f32x4 oacc[2][4] = {};

  const bf16* kg = kb + (size_t)(b * N1) * 1024 + h * DH;
  const bf16* vg = vt + (size_t)((b * HEADS + h) * DH) * N1;
  bf16* Ps = QP + wv * 2048;  // wave's own 32 Q rows (Q already in regs)

  for (int t = 0; t < KEYS_PER_SPLIT / 64; t++) {
    int key0 = sp * KEYS_PER_SPLIT + t * 64;
    __syncthreads();
    for (int j = 0; j < 2; j++) {
      int r0 = j * 32 + wv * 8;
      int r = r0 + (lane >> 3);
      int cs = ((lane & 7) ^ (r & 7)) * 8;
      async16(&kg[(size_t)(key0 + r) * 1024 + cs], &Ks[r0 * 64]);
      async16(&vg[(size_t)r * N1 + key0 + cs], &Vs[r0 * 64]);
    }
    __syncthreads();

    // hoist K/V fragments once, reuse across both q-groups
    bf16x8 ak[2][4], bv[2][4];
    for (int kk = 0; kk < 2; kk++)
      for (int nt = 0; nt < 4; nt++) {
        int row = nt * 16 + lr;
        ak[kk][nt] =
            *(const bf16x8*)&Ks[row * 64 + ((quad + 4 * kk) ^ (row & 7)) * 8];
        bv[kk][nt] =
            *(const bf16x8*)&Vs[row * 64 + ((quad + 4 * kk) ^ (row & 7)) * 8];
      }

    for (int g = 0; g < 2; g++) {
      f32x4 s[4] = {};
      for (int kk = 0; kk < 2; kk++)
        for (int nt = 0; nt < 4; nt++)
          s[nt] = __builtin_amdgcn_mfma_f32_16x16x32_bf16(ak[kk][nt], aQ[g][kk],
                                                          s[nt], 0, 0, 0);
      // per-lane softmax for query = lr (16 keys in regs, reduce across quads)
      float mx = s[0][0];
      for (int nt = 0; nt < 4; nt++)
        for (int r = 0; r < 4; r++) mx = fmaxf(mx, s[nt][r]);
      mx = fmaxf(mx, __shfl_xor(mx, 16, 64));
      mx = fmaxf(mx, __shfl_xor(mx, 32, 64));
      float mn = fmaxf(m_s[g], mx);
      float al = exp2f(m_s[g] - mn);
      float p[4][4], sum = 0.0f;
      for (int nt = 0; nt < 4; nt++)
        for (int r = 0; r < 4; r++) {
          p[nt][r] = exp2f(s[nt][r] - mn);
          sum += p[nt][r];
        }
      sum += __shfl_xor(sum, 16, 64);
      sum += __shfl_xor(sum, 32, 64);
      l_s[g] = l_s[g] * al + sum;
      m_s[g] = mn;
      if (quad == 0) abuf[wv][lr] = al;

      // packed P writes: P[query=lr][key=16nt+4quad+r]
      for (int nt = 0; nt < 4; nt++) {
        bf16x4 pk;
        for (int r = 0; r < 4; r++) pk[r] = (bf16)p[nt][r];
        *(bf16x4*)&Ps[lr * 64 + ((2 * nt + (quad >> 1)) ^ (lr & 7)) * 8 +
                      (quad & 1) * 4] = pk;
      }

      // rescale O accumulator (rows = query = quad*4+r)
      f32x4 a4 = *(const f32x4*)&abuf[wv][quad * 4];
      for (int in = 0; in < 4; in++)
        for (int r = 0; r < 4; r++) oacc[g][in][r] *= a4[r];

      bf16x8 aP[2];
      for (int kk = 0; kk < 2; kk++)
        aP[kk] = *(const bf16x8*)&Ps[lr * 64 + ((4 * kk + quad) ^ (lr & 7)) * 8];
      for (int kk = 0; kk < 2; kk++)
        for (int in = 0; in < 4; in++)
          oacc[g][in] = __builtin_amdgcn_mfma_f32_16x16x32_bf16(
              aP[kk], bv[kk][in], oacc[g][in], 0, 0, 0);
    }
  }

  // epilogue: normalized bf16 partials + lse
  bf16* ob = opb + (size_t)sp * SPLIT_ELEMS;
  size_t rbase = (size_t)(b * HEADS + h) * N2;
  for (int g = 0; g < 2; g++) {
    for (int r = 0; r < 4; r++) {
      float lrow = __shfl(l_s[g], quad * 4 + r, 16);
      float inv = 1.0f / lrow;
      int qq = q0 + wv * 32 + g * 16 + quad * 4 + r;
      for (int in = 0; in < 4; in++)
        ob[(rbase + qq) * 64 + in * 16 + lr] = (bf16)(oacc[g][in][r] * inv);
    }
    if (quad == 0) {
      int qq = q0 + wv * 32 + g * 16 + lr;
      lseb[(size_t)sp * ROWS_TOTAL + rbase + qq] = m_s[g] + __log2f(l_s[g]);
    }
  }
}

// ---------------------------------------------------------------------------
// Combine: out = sum_s W_s Ô_s / sum_s W_s,  W_s = 2^(lse_s - max lse)
// ---------------------------------------------------------------------------
__global__ __launch_bounds__(256) void combine_kernel(const bf16* __restrict__ opb,
                                                      const float* __restrict__ lseb,
                                                      bf16* __restrict__ out) {
  int gid = blockIdx.x * 256 + threadIdx.x;
  int d = gid & 63;
  int rq = gid >> 6;  // (b*16+h)*256 + q
  int qq = rq & 255, bh = rq >> 8;
  int h = bh & 15, b = bh >> 4;
  float ls[ASPLIT];
  for (int s = 0; s < ASPLIT; s++) ls[s] = lseb[(size_t)s * ROWS_TOTAL + rq];
  float M = fmaxf(fmaxf(ls[0], ls[1]), fmaxf(ls[2], ls[3]));
  float L = 0.0f, o = 0.0f;
  for (int s = 0; s < ASPLIT; s++) {
    float w = exp2f(ls[s] - M);
    L += w;
    o += w * (float)opb[(size_t)s * SPLIT_ELEMS + (size_t)rq * 64 + d];
  }
  out[((size_t)(b * N2 + qq)) * INNER + h * DH + d] = (bf16)(o / L);
}

// ---------------------------------------------------------------------------
extern "C" void kernel_launch(void* const* d_in, const int* in_sizes, int n_in,
                              void* d_out, int out_size, void* d_ws,
                              size_t ws_size, hipStream_t stream) {
  const float* x       = (const float*)d_in[0];
  const float* latents = (const float*)d_in[1];
  const float* shift   = (const float*)d_in[2];
  const float* scale   = (const float*)d_in[3];
  const float* ln1w    = (const float*)d_in[4];
  const float* ln1b    = (const float*)d_in[5];
  const float* ln2w    = (const float*)d_in[6];
  const float* ln2b    = (const float*)d_in[7];
  const float* Wq      = (const float*)d_in[8];
  const float* Wkv     = (const float*)d_in[9];
  const float* Wout    = (const float*)d_in[10];

  char* ws = (char*)d_ws;
  bf16*  xn    = (bf16*)(ws);                // 33.5MB; dead after gemm_kvq
  bf16*  opb   = (bf16*)(ws);                //   overlay: 4 bf16 splits 33.5MB
  bf16*  lnl   = (bf16*)(ws + 33554432);     // 2MB; dead after gemm_kvq
  float* lseb  = (float*)(ws + 33554432);    //   overlay: lse 256KB
  bf16*  qb    = (bf16*)(ws + 35651584);     // 2MB
  bf16*  kb    = (bf16*)(ws + 37748736);     // 33.5MB (K half)
  bf16*  vtb   = (bf16*)(ws + 104857600);    // 33.5MB (V^T)
  bf16*  aob   = (bf16*)(ws + 138412032);    // 2MB
  bf16*  WqT   = (bf16*)(ws + 140509184);    // 2MB
  bf16*  WkvT  = (bf16*)(ws + 142606336);    // 4MB
  bf16*  WoutT = (bf16*)(ws + 146800640);    // 2MB

  prep<<<8448, 256, 0, stream>>>(Wq, Wkv, Wout, WqT, WkvT, WoutT, x, latents,
                                 ln1w, ln1b, ln2w, ln2b, xn, lnl);
  gemm_kvq<<<2304, 256, 0, stream>>>(xn, WkvT, kb, vtb, lnl, WqT, qb, shift,
                                     scale);
  attn_kernel<<<dim3(2 * ASPLIT, 16, 4), 256, 0, stream>>>(qb, kb, vtb, opb,
                                                           lseb);
  combine_kernel<<<16384, 256, 0, stream>>>(opb, lseb, aob);
  gemm_out<<<dim3(16, 16), 256, 0, stream>>>(aob, WoutT, (float*)d_out);
}

// Round 8
// 285.316 us; speedup vs baseline: 1.1449x; 1.0110x over previous
//
#include <hip/hip_runtime.h>

typedef __bf16 bf16;
typedef bf16 bf16x8 __attribute__((ext_vector_type(8)));
typedef bf16 bf16x4 __attribute__((ext_vector_type(4)));
typedef float f32x4 __attribute__((ext_vector_type(4)));

#define B_ 4
#define N1 4096
#define N2 256
#define DIM 1024
#define HEADS 16
#define DH 64
#define INNER 1024
#define ASPLIT 4
#define KEYS_PER_SPLIT (N1 / ASPLIT)      // 1024
#define SPLIT_ELEMS (4 * 16 * 256 * 64)   // elems per split partial (bf16)
#define ROWS_TOTAL (4 * HEADS * N2)       // 16384 rows per split

// async global->LDS, 16B per lane; LDS dest = wave-uniform base + lane*16
typedef __attribute__((address_space(1))) const void gvoid_t;
typedef __attribute__((address_space(3))) void lvoid_t;
__device__ __forceinline__ void async16(const void* g, void* l) {
  __builtin_amdgcn_global_load_lds((gvoid_t*)g, (lvoid_t*)l, 16, 0, 0);
}

// ---------------------------------------------------------------------------
// prep: fused weight transposes + both LayerNorms in one launch.
// blocks [0,4096): fp32 (1024 x N) -> bf16 (N x 1024) transpose (Wq/Wkv/Wout)
// blocks [4096,8448): wave-per-row LN (16384 x rows + 1024 latent rows)
// ---------------------------------------------------------------------------
__global__ __launch_bounds__(256) void prep(
    const float* __restrict__ Wq, const float* __restrict__ Wkv,
    const float* __restrict__ Wout, bf16* __restrict__ WqT,
    bf16* __restrict__ WkvT, bf16* __restrict__ WoutT,
    const float* __restrict__ x, const float* __restrict__ latents,
    const float* __restrict__ ln1w, const float* __restrict__ ln1b,
    const float* __restrict__ ln2w, const float* __restrict__ ln2b,
    bf16* __restrict__ xn, bf16* __restrict__ lnl) {
  __shared__ float tile[32][33];
  int t = blockIdx.x;
  if (t < 4096) {  // ---- transpose path ----
    const float* src;
    bf16* dst;
    int N;
    if (t < 1024) { src = Wq; dst = WqT; N = 1024; }
    else if (t < 3072) { t -= 1024; src = Wkv; dst = WkvT; N = 2048; }
    else { t -= 3072; src = Wout; dst = WoutT; N = 1024; }
    int ntiles = N >> 5;
    int n0 = (t % ntiles) * 32, k0 = (t / ntiles) * 32;
    int xx = threadIdx.x & 31, yy = threadIdx.x >> 5;
    for (int j = 0; j < 4; j++)
      tile[yy + 8 * j][xx] = src[(size_t)(k0 + yy + 8 * j) * N + n0 + xx];
    __syncthreads();
    for (int j = 0; j < 4; j++)
      dst[(size_t)(n0 + yy + 8 * j) * 1024 + k0 + xx] = (bf16)tile[xx][yy + 8 * j];
    return;
  }
  // ---- LN path: grid tail = 16384/4 + 1024/4 = 4352 blocks ----
  int wv = threadIdx.x >> 6, lane = threadIdx.x & 63;
  int grow = (t - 4096) * 4 + wv;
  const float *src, *w, *bb;
  bf16* dst;
  int row;
  if (grow < 16384) { src = x; w = ln1w; bb = ln1b; dst = xn; row = grow; }
  else { src = latents; w = ln2w; bb = ln2b; dst = lnl; row = grow - 16384; }
  const float4* p = (const float4*)(src + (size_t)row * DIM);
  float4 v[4];
  for (int j = 0; j < 4; j++) v[j] = p[j * 64 + lane];
  float s = 0.f, sq = 0.f;
  for (int j = 0; j < 4; j++) {
    s += v[j].x + v[j].y + v[j].z + v[j].w;
    sq += v[j].x * v[j].x + v[j].y * v[j].y + v[j].z * v[j].z + v[j].w * v[j].w;
  }
  for (int off = 32; off; off >>= 1) {
    s += __shfl_xor(s, off, 64);
    sq += __shfl_xor(sq, off, 64);
  }
  float mu = s * (1.0f / DIM);
  float var = sq * (1.0f / DIM) - mu * mu;
  float r = rsqrtf(var + 1e-5f);
  for (int j = 0; j < 4; j++) {
    float4 wv4 = ((const float4*)w)[j * 64 + lane];
    float4 bv4 = ((const float4*)bb)[j * 64 + lane];
    bf16x4 o;
    o[0] = (bf16)((v[j].x - mu) * r * wv4.x + bv4.x);
    o[1] = (bf16)((v[j].y - mu) * r * wv4.y + bv4.y);
    o[2] = (bf16)((v[j].z - mu) * r * wv4.z + bv4.z);
    o[3] = (bf16)((v[j].w - mu) * r * wv4.w + bv4.w);
    *(bf16x4*)(dst + (size_t)row * DIM + (j * 64 + lane) * 4) = o;
  }
}

// ---------------------------------------------------------------------------
// Big GEMM (kv only): C = A(MxK) @ Bt(NxK)^T, 128x128 tile, BK=64.
// XCD-aware bid remap: each XCD (bid%8) owns a disjoint m-set, sweeps n with
// an 8-block m-group L2-resident. n0<1024 -> K half (direct bf16);
// n0>=1024 -> V half LDS-transposed to vt[(b*1024+c)*4096+key].
// ---------------------------------------------------------------------------
__global__ __launch_bounds__(256) void gemm_kv(
    const bf16* __restrict__ A, const bf16* __restrict__ Bt,
    bf16* __restrict__ Cout, bf16* __restrict__ Cout2, int K) {
  __shared__ __align__(16) bf16 smem[128 * 64 * 2];  // As | Bs (32KB)
  bf16* As = smem;
  bf16* Bs = smem + 128 * 64;
  int tid = threadIdx.x;
  int lane = tid & 63, wv = tid >> 6;
  int wr = wv >> 1, wc = wv & 1;
  int quad = lane >> 4, lr = lane & 15;
  int bid = blockIdx.y * 16 + blockIdx.x;  // 0..2047
  int c = bid & 7, g = bid >> 3;
  int mi = g & 7, nb = (g >> 3) & 15, chunk = g >> 7;
  int m0 = (chunk * 64 + mi * 8 + c) * 128;
  int n0 = nb * 128;
  f32x4 acc[4][4] = {};
  for (int kt = 0; kt < K; kt += 64) {
    __syncthreads();
    for (int j = 0; j < 4; j++) {
      int idx0 = j * 256 + wv * 64;  // wave-uniform chunk base
      int row = (idx0 >> 3) + (lane >> 3);
      int cb = (lane & 7) ^ (row & 7);  // global col-block for phys blk lane&7
      async16(&A[(size_t)(m0 + row) * K + kt + cb * 8], &As[idx0 * 8]);
      async16(&Bt[(size_t)(n0 + row) * K + kt + cb * 8], &Bs[idx0 * 8]);
    }
    __syncthreads();
    for (int kk = 0; kk < 2; kk++) {
      bf16x8 af[4], bfr[4];
      for (int im = 0; im < 4; im++) {
        int row = wr * 64 + im * 16 + lr;
        af[im] = *(const bf16x8*)&As[row * 64 + ((quad + 4 * kk) ^ (row & 7)) * 8];
      }
      for (int in = 0; in < 4; in++) {
        int row = wc * 64 + in * 16 + lr;
        bfr[in] = *(const bf16x8*)&Bs[row * 64 + ((quad + 4 * kk) ^ (row & 7)) * 8];
      }
      for (int im = 0; im < 4; im++)
        for (int in = 0; in < 4; in++)
          acc[im][in] = __builtin_amdgcn_mfma_f32_16x16x32_bf16(
              af[im], bfr[in], acc[im][in], 0, 0, 0);
    }
  }

  if (n0 >= 1024) {
    // V half: transpose through LDS, write V^T with b128 stores
    bf16* Ct = smem;  // 64 x 136 pitch (17KB)
    for (int pass = 0; pass < 2; pass++) {
      __syncthreads();
      for (int inL = 0; inL < 2; inL++) {
        int in = pass * 2 + inL;
        int cc = wc * 32 + inL * 16 + lr;
        for (int im = 0; im < 4; im++) {
          int rb = wr * 64 + im * 16 + quad * 4;
          bf16x4 pk;
          for (int r = 0; r < 4; r++) pk[r] = (bf16)acc[im][in][r];
          *(bf16x4*)&Ct[cc * 136 + rb] = pk;
        }
      }
      __syncthreads();
      for (int k2 = 0; k2 < 4; k2++) {
        int ci = k2 * 256 + tid;
        int cc = ci >> 4, ch = ci & 15;
        uint4 val = *(const uint4*)&Ct[cc * 136 + ch * 8];
        int gco = (cc >> 5) * 64 + pass * 32 + (cc & 31);
        int col = n0 - 1024 + gco;  // 0..1023 within inner dim
        int bb2 = m0 >> 12;         // batch
        int key = (m0 & 4095) + ch * 8;
        *(uint4*)&Cout2[((size_t)(bb2 * 1024 + col)) * 4096 + key] = val;
      }
    }
    return;
  }

  for (int im = 0; im < 4; im++)
    for (int in = 0; in < 4; in++) {
      int col = n0 + wc * 64 + in * 16 + lr;
      for (int r = 0; r < 4; r++) {
        int row = m0 + wr * 64 + im * 16 + quad * 4 + r;
        Cout[(size_t)row * 1024 + col] = (bf16)acc[im][in][r];
      }
    }
}

// ---------------------------------------------------------------------------
// Small GEMM: 64x64 tile, BK=64, full-chip 256-block grids.
// MODE 1: AdaLN modulation * attn_scale * log2e, store bf16
// MODE 2: store fp32
// ---------------------------------------------------------------------------
template <int MODE>
__global__ __launch_bounds__(256) void gemm64(
    const bf16* __restrict__ A, const bf16* __restrict__ Bt,
    void* __restrict__ Cout, int K, int N,
    const float* __restrict__ shiftp, const float* __restrict__ scalep) {
  __shared__ __align__(16) bf16 As[64 * 64];
  __shared__ __align__(16) bf16 Bs[64 * 64];
  int tid = threadIdx.x;
  int lane = tid & 63, wv = tid >> 6;
  int wr = wv >> 1, wc = wv & 1;
  int quad = lane >> 4, lr = lane & 15;
  int m0 = blockIdx.y * 64, n0 = blockIdx.x * 64;
  f32x4 acc[2][2] = {};
  for (int kt = 0; kt < K; kt += 64) {
    __syncthreads();
    for (int j = 0; j < 2; j++) {
      int idx0 = j * 256 + wv * 64;
      int row = (idx0 >> 3) + (lane >> 3);
      int cb = (lane & 7) ^ (row & 7);
      async16(&A[(size_t)(m0 + row) * K + kt + cb * 8], &As[idx0 * 8]);
      async16(&Bt[(size_t)(n0 + row) * K + kt + cb * 8], &Bs[idx0 * 8]);
    }
    __syncthreads();
    for (int kk = 0; kk < 2; kk++) {
      bf16x8 af[2], bfr[2];
      for (int im = 0; im < 2; im++) {
        int row = wr * 32 + im * 16 + lr;
        af[im] = *(const bf16x8*)&As[row * 64 + ((quad + 4 * kk) ^ (row & 7)) * 8];
      }
      for (int in = 0; in < 2; in++) {
        int row = wc * 32 + in * 16 + lr;
        bfr[in] = *(const bf16x8*)&Bs[row * 64 + ((quad + 4 * kk) ^ (row & 7)) * 8];
      }
      for (int im = 0; im < 2; im++)
        for (int in = 0; in < 2; in++)
          acc[im][in] = __builtin_amdgcn_mfma_f32_16x16x32_bf16(
              af[im], bfr[in], acc[im][in], 0, 0, 0);
    }
  }
  for (int im = 0; im < 2; im++)
    for (int in = 0; in < 2; in++) {
      int col = n0 + wc * 32 + in * 16 + lr;
      for (int r = 0; r < 4; r++) {
        int row = m0 + wr * 32 + im * 16 + quad * 4 + r;
        float v = acc[im][in][r];
        if (MODE == 1) {
          int bb = row >> 8, hh = col >> 6;
          float sc = scalep[bb * 16 + hh], sh = shiftp[bb * 16 + hh];
          // fold attn_scale (0.125) AND log2(e) so softmax uses exp2
          ((bf16*)Cout)[(size_t)row * N + col] =
              (bf16)((v * (1.0f + sc) + sh) * 0.18033688011112042f);
        } else {
          ((float*)Cout)[(size_t)row * N + col] = v;
        }
      }
    }
}

// ---------------------------------------------------------------------------
// Flash attention: block = (b, h, 2 q-tiles, split) -> 512 blocks, 2/CU.
// Each wave owns 32 queries (2 groups of 16); K/V fragments hoisted once per
// 64-key tile and reused across both q-groups. S^T = K·Q^T (lane owns one
// query: scalar m/l, 2-shuffle reductions, packed b64 P writes; P scratch
// overlays the wave's OWN Q rows — exclusive, no cross-wave race).
// Outputs: normalized bf16 partial Ô_s and lse_s = m + log2(l).
// ---------------------------------------------------------------------------
__global__ __launch_bounds__(256) void attn_kernel(const bf16* __restrict__ q,
                                                   const bf16* __restrict__ kb,
                                                   const bf16* __restrict__ vt,
                                                   bf16* __restrict__ opb,
                                                   float* __restrict__ lseb) {
  int b = blockIdx.z, h = blockIdx.y;
  int qp = blockIdx.x >> 2, sp = blockIdx.x & 3;
  int tid = threadIdx.x, lane = tid & 63, wv = tid >> 6;
  int quad = lane >> 4, lr = lane & 15;
  __shared__ __align__(16) bf16 Ks[64 * 64];
  __shared__ __align__(16) bf16 Vs[64 * 64];    // [dh][key]
  __shared__ __align__(16) bf16 QP[128 * 64];   // 128 Q rows; P overlays own rows
  __shared__ float abuf[4][16];
  int q0 = qp * 128;

  // stage 128 Q rows (4 async16/thread)
  const bf16* qg = q + (size_t)(b * N2 + q0) * INNER + h * DH;
  for (int j = 0; j < 4; j++) {
    int r0 = j * 32 + wv * 8;
    int r = r0 + (lane >> 3);
    async16(&qg[(size_t)r * INNER + ((lane & 7) ^ (r & 7)) * 8], &QP[r0 * 64]);
  }
  __syncthreads();
  bf16x8 aQ[2][2];
  for (int g = 0; g < 2; g++) {
    int row = wv * 32 + g * 16 + lr;
    for (int kk = 0; kk < 2; kk++)
      aQ[g][kk] = *(const bf16x8*)&QP[row * 64 + ((quad + 4 * kk) ^ (row & 7)) * 8];
  }
  float m_s[2] = {-1e30f, -1e30f}, l_s[2] = {0.0f, 0.0f};
  f32x4 oacc[2][4] = {};

  const bf16* kg = kb + (size_t)(b * N1) * 1024 + h * DH;
  const bf16* vg = vt + (size_t)((b * HEADS + h) * DH) * N1;
  bf16* Ps = QP + wv * 2048;  // wave's own 32 Q rows (Q already in regs)

  for (int t = 0; t < KEYS_PER_SPLIT / 64; t++) {
    int key0 = sp * KEYS_PER_SPLIT + t * 64;
    __syncthreads();
    for (int j = 0; j < 2; j++) {
      int r0 = j * 32 + wv * 8;
      int r = r0 + (lane >> 3);
      int cs = ((lane & 7) ^ (r & 7)) * 8;
      async16(&kg[(size_t)(key0 + r) * 1024 + cs], &Ks[r0 * 64]);
      async16(&vg[(size_t)r * N1 + key0 + cs], &Vs[r0 * 64]);
    }
    __syncthreads();

    // hoist K/V fragments once, reuse across both q-groups
    bf16x8 ak[2][4], bv[2][4];
    for (int kk = 0; kk < 2; kk++)
      for (int nt = 0; nt < 4; nt++) {
        int row = nt * 16 + lr;
        ak[kk][nt] =
            *(const bf16x8*)&Ks[row * 64 + ((quad + 4 * kk) ^ (row & 7)) * 8];
        bv[kk][nt] =
            *(const bf16x8*)&Vs[row * 64 + ((quad + 4 * kk) ^ (row & 7)) * 8];
      }

    for (int g = 0; g < 2; g++) {
      f32x4 s[4] = {};
      for (int kk = 0; kk < 2; kk++)
        for (int nt = 0; nt < 4; nt++)
          s[nt] = __builtin_amdgcn_mfma_f32_16x16x32_bf16(ak[kk][nt], aQ[g][kk],
                                                          s[nt], 0, 0, 0);
      // per-lane softmax for query = lr (16 keys in regs, reduce across quads)
      float mx = s[0][0];
      for (int nt = 0; nt < 4; nt++)
        for (int r = 0; r < 4; r++) mx = fmaxf(mx, s[nt][r]);
      mx = fmaxf(mx, __shfl_xor(mx, 16, 64));
      mx = fmaxf(mx, __shfl_xor(mx, 32, 64));
      float mn = fmaxf(m_s[g], mx);
      float al = exp2f(m_s[g] - mn);
      float p[4][4], sum = 0.0f;
      for (int nt = 0; nt < 4; nt++)
        for (int r = 0; r < 4; r++) {
          p[nt][r] = exp2f(s[nt][r] - mn);
          sum += p[nt][r];
        }
      sum += __shfl_xor(sum, 16, 64);
      sum += __shfl_xor(sum, 32, 64);
      l_s[g] = l_s[g] * al + sum;
      m_s[g] = mn;
      if (quad == 0) abuf[wv][lr] = al;

      // packed P writes: P[query=lr][key=16nt+4quad+r]
      for (int nt = 0; nt < 4; nt++) {
        bf16x4 pk;
        for (int r = 0; r < 4; r++) pk[r] = (bf16)p[nt][r];
        *(bf16x4*)&Ps[lr * 64 + ((2 * nt + (quad >> 1)) ^ (lr & 7)) * 8 +
                      (quad & 1) * 4] = pk;
      }

      // rescale O accumulator (rows = query = quad*4+r)
      f32x4 a4 = *(const f32x4*)&abuf[wv][quad * 4];
      for (int in = 0; in < 4; in++)
        for (int r = 0; r < 4; r++) oacc[g][in][r] *= a4[r];

      bf16x8 aP[2];
      for (int kk = 0; kk < 2; kk++)
        aP[kk] = *(const bf16x8*)&Ps[lr * 64 + ((4 * kk + quad) ^ (lr & 7)) * 8];
      for (int kk = 0; kk < 2; kk++)
        for (int in = 0; in < 4; in++)
          oacc[g][in] = __builtin_amdgcn_mfma_f32_16x16x32_bf16(
              aP[kk], bv[kk][in], oacc[g][in], 0, 0, 0);
    }
  }

  // epilogue: normalized bf16 partials + lse
  bf16* ob = opb + (size_t)sp * SPLIT_ELEMS;
  size_t rbase = (size_t)(b * HEADS + h) * N2;
  for (int g = 0; g < 2; g++) {
    for (int r = 0; r < 4; r++) {
      float lrow = __shfl(l_s[g], quad * 4 + r, 16);
      float inv = 1.0f / lrow;
      int qq = q0 + wv * 32 + g * 16 + quad * 4 + r;
      for (int in = 0; in < 4; in++)
        ob[(rbase + qq) * 64 + in * 16 + lr] = (bf16)(oacc[g][in][r] * inv);
    }
    if (quad == 0) {
      int qq = q0 + wv * 32 + g * 16 + lr;
      lseb[(size_t)sp * ROWS_TOTAL + rbase + qq] = m_s[g] + __log2f(l_s[g]);
    }
  }
}

// ---------------------------------------------------------------------------
// Combine: out = sum_s W_s Ô_s / sum_s W_s,  W_s = 2^(lse_s - max lse)
// ---------------------------------------------------------------------------
__global__ __launch_bounds__(256) void combine_kernel(const bf16* __restrict__ opb,
                                                      const float* __restrict__ lseb,
                                                      bf16* __restrict__ out) {
  int gid = blockIdx.x * 256 + threadIdx.x;
  int d = gid & 63;
  int rq = gid >> 6;  // (b*16+h)*256 + q
  int qq = rq & 255, bh = rq >> 8;
  int h = bh & 15, b = bh >> 4;
  float ls[ASPLIT];
  for (int s = 0; s < ASPLIT; s++) ls[s] = lseb[(size_t)s * ROWS_TOTAL + rq];
  float M = fmaxf(fmaxf(ls[0], ls[1]), fmaxf(ls[2], ls[3]));
  float L = 0.0f, o = 0.0f;
  for (int s = 0; s < ASPLIT; s++) {
    float w = exp2f(ls[s] - M);
    L += w;
    o += w * (float)opb[(size_t)s * SPLIT_ELEMS + (size_t)rq * 64 + d];
  }
  out[((size_t)(b * N2 + qq)) * INNER + h * DH + d] = (bf16)(o / L);
}

// ---------------------------------------------------------------------------
extern "C" void kernel_launch(void* const* d_in, const int* in_sizes, int n_in,
                              void* d_out, int out_size, void* d_ws,
                              size_t ws_size, hipStream_t stream) {
  const float* x       = (const float*)d_in[0];
  const float* latents = (const float*)d_in[1];
  const float* shift   = (const float*)d_in[2];
  const float* scale   = (const float*)d_in[3];
  const float* ln1w    = (const float*)d_in[4];
  const float* ln1b    = (const float*)d_in[5];
  const float* ln2w    = (const float*)d_in[6];
  const float* ln2b    = (const float*)d_in[7];
  const float* Wq      = (const float*)d_in[8];
  const float* Wkv     = (const float*)d_in[9];
  const float* Wout    = (const float*)d_in[10];

  char* ws = (char*)d_ws;
  bf16*  xn    = (bf16*)(ws);                // 33.5MB; dead after gemm_kv
  bf16*  opb   = (bf16*)(ws);                //   overlay: 4 bf16 splits 33.5MB
  bf16*  lnl   = (bf16*)(ws + 33554432);     // 2MB; dead after q gemm
  float* lseb  = (float*)(ws + 33554432);    //   overlay: lse 256KB
  bf16*  qb    = (bf16*)(ws + 35651584);     // 2MB
  bf16*  kb    = (bf16*)(ws + 37748736);     // 33.5MB (K half)
  bf16*  vtb   = (bf16*)(ws + 104857600);    // 33.5MB (V^T)
  bf16*  aob   = (bf16*)(ws + 138412032);    // 2MB
  bf16*  WqT   = (bf16*)(ws + 140509184);    // 2MB
  bf16*  WkvT  = (bf16*)(ws + 142606336);    // 4MB
  bf16*  WoutT = (bf16*)(ws + 146800640);    // 2MB

  prep<<<8448, 256, 0, stream>>>(Wq, Wkv, Wout, WqT, WkvT, WoutT, x, latents,
                                 ln1w, ln1b, ln2w, ln2b, xn, lnl);
  gemm_kv<<<dim3(16, 128), 256, 0, stream>>>(xn, WkvT, kb, vtb, 1024);
  gemm64<1><<<dim3(16, 16), 256, 0, stream>>>(lnl, WqT, qb, 1024, 1024, shift,
                                              scale);
  attn_kernel<<<dim3(2 * ASPLIT, 16, 4), 256, 0, stream>>>(qb, kb, vtb, opb,
                                                           lseb);
  combine_kernel<<<16384, 256, 0, stream>>>(opb, lseb, aob);
  gemm64<2><<<dim3(16, 16), 256, 0, stream>>>(aob, WoutT, d_out, 1024, 1024,
                                              nullptr, nullptr);
}